// Round 3
// baseline (3153.801 us; speedup 1.0000x reference)
//
#include <hip/hip_runtime.h>
#include <hip/hip_bf16.h>

typedef __hip_bfloat16 bf16;

// ---------- small device helpers ----------
__device__ __forceinline__ unsigned short f2bfu(float f) {
    __hip_bfloat16 h = __float2bfloat16(f);
    return *reinterpret_cast<unsigned short*>(&h);
}
__device__ __forceinline__ float us2f(unsigned short u) {
    unsigned int x = ((unsigned int)u) << 16;
    float f;
    __builtin_memcpy(&f, &x, 4);
    return f;
}
__device__ __forceinline__ float geluf(float x) {
    return 0.5f * x * (1.0f + erff(x * 0.70710678118654752440f));
}
__device__ __forceinline__ float sigmf(float x) { return 1.0f / (1.0f + __expf(-x)); }

// Sizes (fixed by the problem)
#define NB 16
#define NC 128
#define NH 128
#define NW 128
#define PLANE (NH * NW)          // 16384
#define NSTAT 262144.0f          // B*H*W per-channel BN count

// ---------- K1: h = gelu(dce_flat @ W1 + b1), [16,128] ----------
__global__ __launch_bounds__(256) void k_dce1(const float* __restrict__ dce,
                                              const float* __restrict__ W1,
                                              const float* __restrict__ b1,
                                              float* __restrict__ out_h) {
    int b = blockIdx.x;
    int t = threadIdx.x;
    int j = t & 127;
    int half = t >> 7;
    __shared__ float sdce[12800];
    __shared__ float sred[256];
    const float* drow = dce + (size_t)b * 12800;
    for (int i = t; i < 3200; i += 256) {
        float4 v = *(const float4*)&drow[i * 4];
        *(float4*)&sdce[i * 4] = v;
    }
    __syncthreads();
    float acc = 0.0f;
    int k0 = half * 6400;
    const float* Wp = W1 + (size_t)k0 * 128 + j;
    for (int k = 0; k < 6400; ++k) acc += sdce[k0 + k] * Wp[(size_t)k * 128];
    sred[t] = acc;
    __syncthreads();
    if (t < 128) {
        float v = sred[t] + sred[t + 128] + b1[j];
        out_h[b * 128 + j] = geluf(v);
    }
}

// ---------- K2: dce_feat = h @ W2 + b2, [16,128] ----------
__global__ __launch_bounds__(128) void k_dce2(const float* __restrict__ h,
                                              const float* __restrict__ W2,
                                              const float* __restrict__ b2,
                                              float* __restrict__ feat) {
    int b = blockIdx.x, j = threadIdx.x;
    __shared__ float sh[128];
    sh[j] = h[b * 128 + j];
    __syncthreads();
    float acc = b2[j];
    for (int k = 0; k < 128; ++k) acc += sh[k] * W2[k * 128 + j];
    feat[b * 128 + j] = acc;
}

// ---------- K3: spatial features via border-corrected sums ----------
__global__ __launch_bounds__(256) void k_spatial(const float* __restrict__ x,
                                                 const float* __restrict__ dw,
                                                 float* __restrict__ spat) {
    int bc = blockIdx.x;  // b*128+c
    int t = threadIdx.x;
    const float* p = x + (size_t)bc * PLANE;
    float f = 0, r0 = 0, r1 = 0, c0 = 0, c1 = 0;
    for (int i = t; i < PLANE; i += 256) {
        float v = p[i];
        int row = i >> 7, col = i & 127;
        f += v;
        if (row == 0) r0 += v;
        if (row == 127) r1 += v;
        if (col == 0) c0 += v;
        if (col == 127) c1 += v;
    }
    __shared__ float s[256];
    __shared__ float red[5];
    float vals[5] = {f, r0, r1, c0, c1};
    for (int k = 0; k < 5; ++k) {
        s[t] = vals[k];
        __syncthreads();
        for (int o = 128; o > 0; o >>= 1) {
            if (t < o) s[t] += s[t + o];
            __syncthreads();
        }
        if (t == 0) red[k] = s[0];
        __syncthreads();
    }
    if (t == 0) {
        int c = bc & 127;
        float full = red[0], row0 = red[1], row127 = red[2], col0 = red[3], col127 = red[4];
        float x00 = p[0];
        float x0e = p[127];
        float xe0 = p[127 * 128];
        float xee = p[127 * 128 + 127];
        float acc = 0.0f;
        for (int kh = 0; kh < 3; ++kh)
            for (int kw = 0; kw < 3; ++kw) {
                int dh = kh - 1, dwv = kw - 1;
                float T = full;
                if (dh == -1) T -= row127;
                else if (dh == 1) T -= row0;
                if (dwv == -1) T -= col127;
                else if (dwv == 1) T -= col0;
                if (dh == -1 && dwv == -1) T += xee;
                if (dh == -1 && dwv == 1) T += xe0;
                if (dh == 1 && dwv == -1) T += x0e;
                if (dh == 1 && dwv == 1) T += x00;
                acc += dw[c * 9 + kh * 3 + kw] * T;
            }
        spat[bc] = acc * (1.0f / 16384.0f);
    }
}

// ---------- K4: SE modulation -> mod_w [16,128] ----------
__global__ __launch_bounds__(128) void k_mod(const float* __restrict__ feat,
                                             const float* __restrict__ spat,
                                             const float* __restrict__ Wsh,
                                             const float* __restrict__ bsh,
                                             const float* __restrict__ Wex,
                                             const float* __restrict__ bex,
                                             float* __restrict__ mod) {
    int b = blockIdx.x, t = threadIdx.x;
    __shared__ float sm[128], ssh[64];
    sm[t] = feat[b * 128 + t] * spat[b * 128 + t];
    __syncthreads();
    if (t < 64) {
        float acc = bsh[t];
        for (int c = 0; c < 128; ++c) acc += sm[c] * Wsh[c * 64 + t];
        ssh[t] = geluf(acc);
    }
    __syncthreads();
    float acc = bex[t];
    for (int k = 0; k < 64; ++k) acc += ssh[k] * Wex[k * 128 + t];
    mod[b * 128 + t] = sigmf(acc);
}

// ---------- K5: conv1 3x3 on xm (write y1 -> d_out, bn1 stats) + sc 1x1 stats ----------
__global__ __launch_bounds__(256) void k_conv1(const float* __restrict__ x,
                                               const float* __restrict__ w1,
                                               const float* __restrict__ wsc,
                                               const float* __restrict__ mod,
                                               float* __restrict__ y1,
                                               float* __restrict__ stats) {
    int bid = blockIdx.x;
    int cog = bid & 3;
    int h = (bid >> 2) & 127;
    int b = bid >> 9;
    int t = threadIdx.x;
    int w_i = t & 31, co_i = t >> 5;
    int wb = w_i * 4;

    __shared__ float A[16][3][132];    // [ci][row][col+1]
    __shared__ float WL[16 * 9 * 32];  // [ci][tap][co]
    __shared__ float WS[16 * 32];      // [ci][co]

    float acc[4][4];
    float asc[4][4];
#pragma unroll
    for (int a = 0; a < 4; ++a)
#pragma unroll
        for (int i = 0; i < 4; ++i) { acc[a][i] = 0.0f; asc[a][i] = 0.0f; }

    for (int cc = 0; cc < 8; ++cc) {
        __syncthreads();
        for (int e = t; e < 16 * 3 * 130; e += 256) {
            int ci = e / 390;
            int rem = e - ci * 390;
            int row = rem / 130;
            int col = rem - row * 130;
            int hr = h + row - 1;
            int wsrc = col - 1;
            int cig = cc * 16 + ci;
            float v = 0.0f;
            if ((unsigned)hr < 128u && (unsigned)wsrc < 128u)
                v = x[(((size_t)b * 128 + cig) * 128 + hr) * 128 + wsrc] * mod[b * 128 + cig];
            A[ci][row][col] = v;
        }
        for (int e = t; e < 16 * 9 * 32; e += 256) {
            int co_l = e & 31;
            int rest = e >> 5;
            int tap = rest % 9;
            int ci = rest / 9;
            WL[e] = w1[(((size_t)(cog * 32 + co_l)) * 128 + (cc * 16 + ci)) * 9 + tap];
        }
        for (int e = t; e < 512; e += 256) {
            int co_l = e & 31;
            int ci = e >> 5;
            WS[e] = wsc[((size_t)(cog * 32 + co_l)) * 128 + (cc * 16 + ci)];
        }
        __syncthreads();

        for (int ci = 0; ci < 16; ++ci) {
#pragma unroll
            for (int kh = 0; kh < 3; ++kh) {
                float4 w4 = *(const float4*)&A[ci][kh][wb];
                float2 w2 = *(const float2*)&A[ci][kh][wb + 4];
                float win[6] = {w4.x, w4.y, w4.z, w4.w, w2.x, w2.y};
#pragma unroll
                for (int kw = 0; kw < 3; ++kw) {
                    float4 wv = *(const float4*)&WL[(ci * 9 + kh * 3 + kw) * 32 + co_i * 4];
#pragma unroll
                    for (int i = 0; i < 4; ++i) {
                        float a = win[i + kw];
                        acc[0][i] += wv.x * a;
                        acc[1][i] += wv.y * a;
                        acc[2][i] += wv.z * a;
                        acc[3][i] += wv.w * a;
                    }
                }
                if (kh == 1) {
                    float4 sv = *(const float4*)&WS[ci * 32 + co_i * 4];
#pragma unroll
                    for (int i = 0; i < 4; ++i) {
                        float a = win[i + 1];
                        asc[0][i] += sv.x * a;
                        asc[1][i] += sv.y * a;
                        asc[2][i] += sv.z * a;
                        asc[3][i] += sv.w * a;
                    }
                }
            }
        }
    }

#pragma unroll
    for (int c4 = 0; c4 < 4; ++c4) {
        int co = cog * 32 + co_i * 4 + c4;
        float4 pk;
        pk.x = acc[c4][0]; pk.y = acc[c4][1]; pk.z = acc[c4][2]; pk.w = acc[c4][3];
        *(float4*)(y1 + (((size_t)b * 128 + co) * 128 + h) * 128 + wb) = pk;

        float s = 0, q = 0, ss = 0, sq = 0;
#pragma unroll
        for (int i = 0; i < 4; ++i) {
            float v = acc[c4][i];
            s += v; q += v * v;
            float u = asc[c4][i];
            ss += u; sq += u * u;
        }
#pragma unroll
        for (int o = 1; o < 32; o <<= 1) {
            s += __shfl_xor(s, o);
            q += __shfl_xor(q, o);
            ss += __shfl_xor(ss, o);
            sq += __shfl_xor(sq, o);
        }
        if ((t & 31) == 0) {
            atomicAdd(&stats[co], s);
            atomicAdd(&stats[128 + co], q);
            atomicAdd(&stats[256 + co], ss);
            atomicAdd(&stats[384 + co], sq);
        }
    }
}

// ---------- K6: finalize bn1 + bnsc -> affine coefs ----------
__global__ __launch_bounds__(256) void k_fin1(const float* __restrict__ stats,
                                              const float* __restrict__ g1, const float* __restrict__ be1,
                                              const float* __restrict__ gsc, const float* __restrict__ bsc,
                                              float* __restrict__ coef) {
    int t = threadIdx.x;
    const float inv = 1.0f / NSTAT;
    if (t < 128) {
        float m = stats[t] * inv;
        float v = stats[128 + t] * inv - m * m;
        float a = g1[t] * rsqrtf(v + 1e-5f);
        coef[t] = a;
        coef[128 + t] = be1[t] - m * a;
    } else {
        int c = t - 128;
        float m = stats[256 + c] * inv;
        float v = stats[384 + c] * inv - m * m;
        float a = gsc[c] * rsqrtf(v + 1e-5f);
        coef[256 + c] = a;
        coef[384 + c] = bsc[c] - m * a;
    }
}

// ---------- K7: conv2 (1x1) over bb=silu(bn1(y1)) -> bn2 stats only ----------
__global__ __launch_bounds__(256) void k_conv2stats(const float* __restrict__ y1,
                                                    const float* __restrict__ w2,
                                                    const float* __restrict__ coef,
                                                    float* __restrict__ stats) {
    int bid = blockIdx.x;
    int cog = bid & 3;
    int h = (bid >> 2) & 127;
    int b = bid >> 9;
    int t = threadIdx.x;
    int w_i = t & 31, co_i = t >> 5;
    int wb = w_i * 4;
    __shared__ float A2[16][128];
    __shared__ float W2L[512];
    float acc[4][4];
#pragma unroll
    for (int a = 0; a < 4; ++a)
#pragma unroll
        for (int i = 0; i < 4; ++i) acc[a][i] = 0.0f;

    for (int cc = 0; cc < 8; ++cc) {
        __syncthreads();
        for (int e = t; e < 2048; e += 256) {
            int ci = e >> 7, col = e & 127;
            int cig = cc * 16 + ci;
            float v = y1[(((size_t)b * 128 + cig) * 128 + h) * 128 + col];
            v = coef[cig] * v + coef[128 + cig];
            A2[ci][col] = v * sigmf(v);
        }
        for (int e = t; e < 512; e += 256) {
            int co_l = e & 31, ci = e >> 5;
            W2L[e] = w2[(size_t)(cog * 32 + co_l) * 128 + cc * 16 + ci];
        }
        __syncthreads();
        for (int ci = 0; ci < 16; ++ci) {
            float4 win = *(const float4*)&A2[ci][wb];
            float4 wv = *(const float4*)&W2L[ci * 32 + co_i * 4];
            float w0 = win.x, w1v = win.y, w2v = win.z, w3 = win.w;
            acc[0][0] += wv.x * w0; acc[0][1] += wv.x * w1v; acc[0][2] += wv.x * w2v; acc[0][3] += wv.x * w3;
            acc[1][0] += wv.y * w0; acc[1][1] += wv.y * w1v; acc[1][2] += wv.y * w2v; acc[1][3] += wv.y * w3;
            acc[2][0] += wv.z * w0; acc[2][1] += wv.z * w1v; acc[2][2] += wv.z * w2v; acc[2][3] += wv.z * w3;
            acc[3][0] += wv.w * w0; acc[3][1] += wv.w * w1v; acc[3][2] += wv.w * w2v; acc[3][3] += wv.w * w3;
        }
    }
#pragma unroll
    for (int c4 = 0; c4 < 4; ++c4) {
        int co = cog * 32 + co_i * 4 + c4;
        float s = 0, q = 0;
#pragma unroll
        for (int i = 0; i < 4; ++i) {
            float v = acc[c4][i];
            s += v; q += v * v;
        }
#pragma unroll
        for (int o = 1; o < 32; o <<= 1) {
            s += __shfl_xor(s, o);
            q += __shfl_xor(q, o);
        }
        if ((t & 31) == 0) {
            atomicAdd(&stats[512 + co], s);
            atomicAdd(&stats[640 + co], q);
        }
    }
}

// ---------- K8: finalize bn2 ----------
__global__ __launch_bounds__(128) void k_fin2(const float* __restrict__ stats,
                                              const float* __restrict__ g2, const float* __restrict__ be2,
                                              float* __restrict__ coef) {
    int c = threadIdx.x;
    const float inv = 1.0f / NSTAT;
    float m = stats[512 + c] * inv;
    float v = stats[640 + c] * inv - m * m;
    float a = g2[c] * rsqrtf(v + 1e-5f);
    coef[512 + c] = a;
    coef[640 + c] = be2[c] - m * a;
}

// ---------- K9: slice-local final: out = silu(bn2(conv2(bb)) + bnsc(sc(xm))) ----------
// One block per (b,h). Stages the full bb slice (b,:,h,:) into LDS (bn1+silu, bf16)
// BEFORE any global writes, then overwrites the same d_out slice. 1x1 convs are
// slice-local -> exact, no inter-block races.
__global__ __launch_bounds__(256) void k_final(const float* __restrict__ x,
                                               float* yio,
                                               const float* __restrict__ w2,
                                               const float* __restrict__ wsc,
                                               const float* __restrict__ mod,
                                               const float* __restrict__ coef) {
    int bid = blockIdx.x;  // b*128 + h
    int h = bid & 127;
    int b = bid >> 7;
    int t = threadIdx.x;
    int w_i = t & 31, co_i = t >> 5;   // co_i in 0..7 -> 16 co each
    int wb = w_i * 4;
    int cb = co_i * 16;

    __shared__ unsigned short bb_s[128][128];  // 32 KB post-bn1-silu (bf16)
    __shared__ float AX[16][128];              // 8 KB xm chunk
    __shared__ float W2L[16 * 128];            // 8 KB [co][ci16]
    __shared__ float WSL[16 * 128];            // 8 KB

    // stage full bb slice BEFORE any global writes
    for (int e = t; e < 16384; e += 256) {
        int ci = e >> 7, col = e & 127;
        float v = yio[(((size_t)b * 128 + ci) * 128 + h) * 128 + col];
        v = coef[ci] * v + coef[128 + ci];
        v = v * sigmf(v);
        bb_s[ci][col] = f2bfu(v);
    }

    float acc2[16][4], accs[16][4];
#pragma unroll
    for (int j = 0; j < 16; ++j)
#pragma unroll
        for (int i = 0; i < 4; ++i) { acc2[j][i] = 0.0f; accs[j][i] = 0.0f; }

    for (int cc = 0; cc < 8; ++cc) {
        __syncthreads();
        for (int e = t; e < 2048; e += 256) {
            int ci = e >> 7, col = e & 127;
            int cig = cc * 16 + ci;
            AX[ci][col] = x[(((size_t)b * 128 + cig) * 128 + h) * 128 + col] * mod[b * 128 + cig];
        }
        for (int e = t; e < 2048; e += 256) {
            int co = e >> 4, ci = e & 15;
            W2L[e] = w2[(size_t)co * 128 + cc * 16 + ci];
            WSL[e] = wsc[(size_t)co * 128 + cc * 16 + ci];
        }
        __syncthreads();

        for (int ci = 0; ci < 16; ++ci) {
            ushort4 bu = *(const ushort4*)&bb_s[cc * 16 + ci][wb];
            float a0 = us2f(bu.x), a1 = us2f(bu.y), a2 = us2f(bu.z), a3 = us2f(bu.w);
            float4 xv = *(const float4*)&AX[ci][wb];
#pragma unroll
            for (int j = 0; j < 16; ++j) {
                float wv = W2L[(cb + j) * 16 + ci];
                float sv = WSL[(cb + j) * 16 + ci];
                acc2[j][0] += wv * a0; acc2[j][1] += wv * a1; acc2[j][2] += wv * a2; acc2[j][3] += wv * a3;
                accs[j][0] += sv * xv.x; accs[j][1] += sv * xv.y; accs[j][2] += sv * xv.z; accs[j][3] += sv * xv.w;
            }
        }
    }

#pragma unroll
    for (int j = 0; j < 16; ++j) {
        int co = cb + j;
        float a2c = coef[512 + co], c2c = coef[640 + co];
        float asc = coef[256 + co], csc = coef[384 + co];
        float4 pk;
        float r[4];
#pragma unroll
        for (int i = 0; i < 4; ++i) {
            float v = a2c * acc2[j][i] + c2c + asc * accs[j][i] + csc;
            r[i] = v * sigmf(v);
        }
        pk.x = r[0]; pk.y = r[1]; pk.z = r[2]; pk.w = r[3];
        *(float4*)(yio + (((size_t)b * 128 + co) * 128 + h) * 128 + wb) = pk;
    }
}

// ---------- launcher ----------
extern "C" void kernel_launch(void* const* d_in, const int* in_sizes, int n_in,
                              void* d_out, int out_size, void* d_ws, size_t ws_size,
                              hipStream_t stream) {
    (void)in_sizes; (void)n_in; (void)out_size; (void)ws_size;
    const float* x    = (const float*)d_in[0];
    const float* dce  = (const float*)d_in[1];
    const float* dwc  = (const float*)d_in[2];
    const float* W1   = (const float*)d_in[3];
    const float* b1   = (const float*)d_in[4];
    const float* W2d  = (const float*)d_in[5];
    const float* b2d  = (const float*)d_in[6];
    const float* Wsh  = (const float*)d_in[7];
    const float* bsh  = (const float*)d_in[8];
    const float* Wex  = (const float*)d_in[9];
    const float* bex  = (const float*)d_in[10];
    const float* c1w  = (const float*)d_in[11];
    const float* g1   = (const float*)d_in[12];
    const float* be1  = (const float*)d_in[13];
    const float* c2w  = (const float*)d_in[14];
    const float* g2   = (const float*)d_in[15];
    const float* be2  = (const float*)d_in[16];
    const float* scw  = (const float*)d_in[17];
    const float* gsc  = (const float*)d_in[18];
    const float* bsc  = (const float*)d_in[19];

    // small float scratch at start of d_ws (~39 KB) — y1 lives in d_out (fp32)
    float* F = (float*)d_ws;
    float* dh    = F;            // 2048
    float* feat  = F + 2048;     // 2048
    float* spat  = F + 4096;     // 2048
    float* md    = F + 6144;     // 2048
    float* stats = F + 8192;     // 768
    float* coef  = F + 8960;     // 768

    float* y1 = (float*)d_out;   // conv1 output staged in d_out, overwritten by k_final

    hipMemsetAsync(stats, 0, 768 * sizeof(float), stream);

    k_dce1<<<16, 256, 0, stream>>>(dce, W1, b1, dh);
    k_dce2<<<16, 128, 0, stream>>>(dh, W2d, b2d, feat);
    k_spatial<<<2048, 256, 0, stream>>>(x, dwc, spat);
    k_mod<<<16, 128, 0, stream>>>(feat, spat, Wsh, bsh, Wex, bex, md);
    k_conv1<<<8192, 256, 0, stream>>>(x, c1w, scw, md, y1, stats);
    k_fin1<<<1, 256, 0, stream>>>(stats, g1, be1, gsc, bsc, coef);
    k_conv2stats<<<8192, 256, 0, stream>>>(y1, c2w, coef, stats);
    k_fin2<<<1, 128, 0, stream>>>(stats, g2, be2, coef);
    k_final<<<2048, 256, 0, stream>>>(x, y1, c2w, scw, md, coef);
}